// Round 4
// baseline (243.486 us; speedup 1.0000x reference)
//
#include <hip/hip_runtime.h>
#include <stdint.h>

typedef __attribute__((ext_vector_type(8))) short short8;
typedef __attribute__((ext_vector_type(4))) float floatx4;

__device__ inline float bf2f(unsigned short b) {
    unsigned u = ((unsigned)b) << 16;
    return __builtin_bit_cast(float, u);
}
__device__ inline unsigned short f2bf(float f) {
    unsigned u = __builtin_bit_cast(unsigned, f);
    unsigned r = (u + 0x7fffu + ((u >> 16) & 1u)) >> 16;
    return (unsigned short)r;
}
__device__ inline float ldf(const void* p, int i, int f32) {
    return f32 ? ((const float*)p)[i] : bf2f(((const unsigned short*)p)[i]);
}
__device__ inline int lde(const int* ei, int idx, int is64) {
    return is64 ? ei[2 * idx] : ei[idx];
}

// ---- K_det: input dtype layouts (deterministic, every launch) ----
__global__ void k_det(const void* x, const int* ei, int* flags) {
    __shared__ int h1, h2;
    if (threadIdx.x == 0) { h1 = 0; h2 = 0; }
    __syncthreads();
    const unsigned short* xs = (const unsigned short*)x;
    int c1 = 0;
    for (int i = threadIdx.x * 2; i < 65536; i += 512)
        if ((xs[i] & 0x7f80u) == 0x7f80u) c1++;   // fp32 mantissa halves ~1/256; bf16 never
    int c2 = 0;
    for (int i = threadIdx.x * 2 + 1; i < 8192; i += 512)
        if (ei[i] != 0) c2++;                      // int64 high words are 0
    atomicAdd(&h1, c1);
    atomicAdd(&h2, c2);
    __syncthreads();
    if (threadIdx.x == 0) { flags[0] = (h1 >= 8); flags[1] = (h2 < 8); }
}

// ---- K0: zero counts ----
__global__ void k0_init(int* counts, int N) {
    int i = blockIdx.x * blockDim.x + threadIdx.x;
    if (i <= N) counts[i] = 0;
}

// ---- K_conv: W -> transposed bf16 hi/lo (once, not per GEMM block) ----
__global__ __launch_bounds__(256) void k_conv(
    const void* __restrict__ W, const int* __restrict__ flags,
    unsigned short* __restrict__ WhT, unsigned short* __restrict__ WlT)
{
    int f32 = flags[0];
    int idx = blockIdx.x * 256 + threadIdx.x;   // 64 blocks
    if (idx >= 128 * 128) return;
    int n = idx >> 7, k = idx & 127;
    float v = ldf(W, k * 128 + n, f32);
    unsigned short h = f2bf(v);
    WhT[idx] = h;
    WlT[idx] = f2bf(v - bf2f(h));
}

// ---- K1: proj = x@W via bf16x3 MFMA, vectorized staging + fused scores ----
__global__ __launch_bounds__(256) void k1_gemm(
    const void* __restrict__ x, const unsigned short* __restrict__ WhT,
    const unsigned short* __restrict__ WlT, const void* __restrict__ a_src,
    const void* __restrict__ a_trg, const int* __restrict__ flags,
    unsigned short* __restrict__ projb, float* __restrict__ ssrc,
    float* __restrict__ strg, int N)
{
    __shared__ __align__(16) unsigned short WT[128 * 136];
    int t = threadIdx.x;
    int f32 = flags[0];
    for (int i = t; i < 2048; i += 256) {
        int row = i >> 4, ch = (i & 15) * 8;
        *(short8*)&WT[row * 136 + ch] = *(const short8*)&WhT[row * 128 + ch];
    }
    __syncthreads();
    int wave = t >> 6, lane = t & 63;
    int col = lane & 15, quad = lane >> 4;
    int row0 = blockIdx.x * 64 + wave * 16;
    int m = row0 + col;
    if (m >= N) m = N - 1;
    short8 ah[4], al[4];
    if (f32) {
        const float* xf = (const float*)x + (size_t)m * 128 + quad * 8;
#pragma unroll
        for (int kb = 0; kb < 4; kb++) {
            float4 v0 = *(const float4*)(xf + kb * 32);
            float4 v1 = *(const float4*)(xf + kb * 32 + 4);
            float vv[8] = {v0.x, v0.y, v0.z, v0.w, v1.x, v1.y, v1.z, v1.w};
#pragma unroll
            for (int j = 0; j < 8; j++) {
                unsigned short h = f2bf(vv[j]);
                ah[kb][j] = (short)h;
                al[kb][j] = (short)f2bf(vv[j] - bf2f(h));
            }
        }
    } else {
        const unsigned short* xb = (const unsigned short*)x + (size_t)m * 128 + quad * 8;
#pragma unroll
        for (int kb = 0; kb < 4; kb++)
            ah[kb] = *(const short8*)(xb + kb * 32);
    }
    floatx4 acc[8];
#pragma unroll
    for (int c = 0; c < 8; c++) acc[c] = (floatx4){0.f, 0.f, 0.f, 0.f};
#pragma unroll
    for (int c = 0; c < 8; c++) {
        const short8* bp = (const short8*)(&WT[(c * 16 + col) * 136 + quad * 8]);
        short8 b0 = bp[0], b1 = bp[4], b2 = bp[8], b3 = bp[12];
        acc[c] = __builtin_amdgcn_mfma_f32_16x16x32_bf16(ah[0], b0, acc[c], 0, 0, 0);
        acc[c] = __builtin_amdgcn_mfma_f32_16x16x32_bf16(ah[1], b1, acc[c], 0, 0, 0);
        acc[c] = __builtin_amdgcn_mfma_f32_16x16x32_bf16(ah[2], b2, acc[c], 0, 0, 0);
        acc[c] = __builtin_amdgcn_mfma_f32_16x16x32_bf16(ah[3], b3, acc[c], 0, 0, 0);
        if (f32) {
            acc[c] = __builtin_amdgcn_mfma_f32_16x16x32_bf16(al[0], b0, acc[c], 0, 0, 0);
            acc[c] = __builtin_amdgcn_mfma_f32_16x16x32_bf16(al[1], b1, acc[c], 0, 0, 0);
            acc[c] = __builtin_amdgcn_mfma_f32_16x16x32_bf16(al[2], b2, acc[c], 0, 0, 0);
            acc[c] = __builtin_amdgcn_mfma_f32_16x16x32_bf16(al[3], b3, acc[c], 0, 0, 0);
        }
    }
    if (f32) {
        __syncthreads();
        for (int i = t; i < 2048; i += 256) {
            int row = i >> 4, ch = (i & 15) * 8;
            *(short8*)&WT[row * 136 + ch] = *(const short8*)&WlT[row * 128 + ch];
        }
        __syncthreads();
#pragma unroll
        for (int c = 0; c < 8; c++) {
            const short8* bp = (const short8*)(&WT[(c * 16 + col) * 136 + quad * 8]);
            acc[c] = __builtin_amdgcn_mfma_f32_16x16x32_bf16(ah[0], bp[0], acc[c], 0, 0, 0);
            acc[c] = __builtin_amdgcn_mfma_f32_16x16x32_bf16(ah[1], bp[4], acc[c], 0, 0, 0);
            acc[c] = __builtin_amdgcn_mfma_f32_16x16x32_bf16(ah[2], bp[8], acc[c], 0, 0, 0);
            acc[c] = __builtin_amdgcn_mfma_f32_16x16x32_bf16(ah[3], bp[12], acc[c], 0, 0, 0);
        }
    }
#pragma unroll
    for (int r = 0; r < 4; r++) {
        int row = row0 + quad * 4 + r;
        if (row < N) {
#pragma unroll
            for (int c = 0; c < 8; c++)
                projb[(size_t)row * 128 + c * 16 + col] = f2bf(acc[c][r]);
        }
    }
    float asv[8], atv[8];
#pragma unroll
    for (int c = 0; c < 8; c++) {
        int j = c * 16 + col;
        asv[c] = ldf(a_src, j, f32);
        atv[c] = ldf(a_trg, j, f32);
    }
#pragma unroll
    for (int r = 0; r < 4; r++) {
        int row = row0 + quad * 4 + r;
        float ps[4] = {0.f, 0.f, 0.f, 0.f}, pt[4] = {0.f, 0.f, 0.f, 0.f};
#pragma unroll
        for (int c = 0; c < 8; c++) {
            int h = c >> 1;
            ps[h] += acc[c][r] * asv[c];
            pt[h] += acc[c][r] * atv[c];
        }
#pragma unroll
        for (int k = 1; k < 16; k <<= 1) {
#pragma unroll
            for (int h = 0; h < 4; h++) {
                ps[h] += __shfl_xor(ps[h], k, 16);
                pt[h] += __shfl_xor(pt[h], k, 16);
            }
        }
        if (col == 0 && row < N) {
#pragma unroll
            for (int h = 0; h < 4; h++) {
                ssrc[(size_t)row * 4 + h] = ps[h];
                strg[(size_t)row * 4 + h] = pt[h];
            }
        }
    }
}

__device__ inline void edge_scores(const float* ssrc, const float* strg,
                                   int src, int trg, float* v) {
    float4 a = *(const float4*)(ssrc + (size_t)src * 4);
    float4 b = *(const float4*)(strg + (size_t)trg * 4);
    v[0] = a.x + b.x; v[1] = a.y + b.y; v[2] = a.z + b.z; v[3] = a.w + b.w;
#pragma unroll
    for (int h = 0; h < 4; h++) v[h] = v[h] > 0.f ? v[h] : 0.2f * v[h];
}

// ---- KE: in-degree histogram + per-block TRUE edge max.
//      The atomic's return value IS the within-segment rank (saves k2c's atomic).
//      NOTE: the true edge max is semantically required — it participates in the
//      reference's (denom + 1e-16) epsilon floor; an upper bound is NOT valid. ----
__global__ __launch_bounds__(256) void kE_count_max(
    const int* __restrict__ ei, const float* __restrict__ ssrc,
    const float* __restrict__ strg, const int* __restrict__ flags,
    int* __restrict__ counts, int* __restrict__ erank,
    float* __restrict__ blockmax, int E, int N)
{
    int e64 = flags[1];
    int e = blockIdx.x * 256 + threadIdx.x;
    float m = -3.0e38f;
    if (e < E) {
        int src = min(max(lde(ei, e, e64), 0), N - 1);
        int trg = min(max(lde(ei, E + e, e64), 0), N - 1);
        erank[e] = atomicAdd(&counts[trg], 1);
        float v[4];
        edge_scores(ssrc, strg, src, trg, v);
        m = fmaxf(fmaxf(v[0], v[1]), fmaxf(v[2], v[3]));
    }
#pragma unroll
    for (int k = 1; k < 64; k <<= 1) m = fmaxf(m, __shfl_xor(m, k, 64));
    __shared__ float wm[4];
    if ((threadIdx.x & 63) == 0) wm[threadIdx.x >> 6] = m;
    __syncthreads();
    if (threadIdx.x == 0)
        blockmax[blockIdx.x] = fmaxf(fmaxf(wm[0], wm[1]), fmaxf(wm[2], wm[3]));
}

// ---- S1: per-block sums of counts (coalesced) ----
__global__ __launch_bounds__(256) void kS1_psum(
    const int* __restrict__ counts, int* __restrict__ partials, int NP1)
{
    int idx = blockIdx.x * 256 + threadIdx.x;
    int v = (idx < NP1) ? counts[idx] : 0;
#pragma unroll
    for (int k = 1; k < 64; k <<= 1) v += __shfl_xor(v, k, 64);
    __shared__ int wsum[4];
    if ((threadIdx.x & 63) == 0) wsum[threadIdx.x >> 6] = v;
    __syncthreads();
    if (threadIdx.x == 0)
        partials[blockIdx.x] = wsum[0] + wsum[1] + wsum[2] + wsum[3];
}

// ---- S2: exclusive scan of partials (<=256) + Mval reduction (1 block) ----
__global__ __launch_bounds__(256) void kS2_scanp(
    int* __restrict__ partials, int nb,
    const float* __restrict__ blockmax, float* __restrict__ Mval, int nbm)
{
    int t = threadIdx.x;
    if (nb <= 256) {
        __shared__ int lds[256];
        int v = (t < nb) ? partials[t] : 0;
        lds[t] = v;
        __syncthreads();
        int incl = v;
        for (int st = 1; st < 256; st <<= 1) {
            int add = (t >= st) ? lds[t - st] : 0;
            __syncthreads();
            incl += add;
            lds[t] = incl;
            __syncthreads();
        }
        if (t < nb) partials[t] = incl - v;
    } else if (t == 0) {
        int run = 0;
        for (int i = 0; i < nb; i++) { int c = partials[i]; partials[i] = run; run += c; }
    }
    __syncthreads();
    float m = -3.0e38f;
    for (int i = t; i < nbm; i += 256) m = fmaxf(m, blockmax[i]);
#pragma unroll
    for (int k = 1; k < 64; k <<= 1) m = fmaxf(m, __shfl_xor(m, k, 64));
    __shared__ float wm[4];
    if ((t & 63) == 0) wm[t >> 6] = m;
    __syncthreads();
    if (t == 0) *Mval = fmaxf(fmaxf(wm[0], wm[1]), fmaxf(wm[2], wm[3]));
}

// ---- S3: per-block exclusive scan + base -> offsets (coalesced) ----
__global__ __launch_bounds__(256) void kS3_offs(
    const int* __restrict__ counts, const int* __restrict__ partials,
    int* __restrict__ offsets, int NP1)
{
    int t = threadIdx.x;
    int idx = blockIdx.x * 256 + t;
    int v = (idx < NP1) ? counts[idx] : 0;
    __shared__ int lds[256];
    lds[t] = v;
    __syncthreads();
    int incl = v;
    for (int st = 1; st < 256; st <<= 1) {
        int add = (t >= st) ? lds[t - st] : 0;
        __syncthreads();
        incl += add;
        lds[t] = incl;
        __syncthreads();
    }
    if (idx < NP1) offsets[idx] = partials[blockIdx.x] + incl - v;
}

// ---- K2c: CSR scatter of src using precomputed ranks (no atomics here) ----
__global__ __launch_bounds__(256) void k2c_scatter(
    const int* __restrict__ ei, const int* __restrict__ offsets,
    const int* __restrict__ flags, const int* __restrict__ erank,
    int* __restrict__ esrc, int E, int N)
{
    int e64 = flags[1];
    int e = blockIdx.x * 256 + threadIdx.x;
    if (e >= E) return;
    int src = min(max(lde(ei, e, e64), 0), N - 1);
    int trg = min(max(lde(ei, E + e, e64), 0), N - 1);
    int pos = offsets[trg] + erank[e];
    if (pos >= 0 && pos < E) esrc[pos] = src;
}

// ---- K3: single-pass softmax-aggregate, 2 edges per wave-iteration.
//      Lanes 0-31 process even pair-edge, lanes 32-63 odd; each lane gathers
//      8 B (4 bf16 features) per edge -> half the per-edge VALU overhead and
//      2x bytes in flight vs the 4 B/lane layout. Cross-half merge via one
//      shfl_xor(32). Wave-independent: no __syncthreads in the loop. ----
__global__ __launch_bounds__(256) void k3_agg(
    const int* __restrict__ offsets, const int* __restrict__ esrc,
    const float* __restrict__ ssrc, const float* __restrict__ strg,
    const unsigned short* __restrict__ projb, const void* __restrict__ x,
    const void* __restrict__ bias, const int* __restrict__ flags,
    const float* __restrict__ Mval, float* __restrict__ out, int N, int E)
{
    int w = threadIdx.x >> 6;
    int lane = threadIdx.x & 63;
    int n = blockIdx.x * 4 + w;
    int f32 = flags[0];
    if (n >= N) return;
    int off = offsets[n];
    int d = offsets[n + 1] - off;
    d = max(0, min(d, E));
    float M = *Mval;
    float4 stv = *(const float4*)(strg + (size_t)n * 4);
    float st[4] = {stv.x, stv.y, stv.z, stv.w};

    __shared__ int lsrc[4][64];
    __shared__ float latt[4][64 * 5];

    int half = lane >> 5;   // which edge of the current pair this lane serves
    int sl = lane & 31;     // feature group: features sl*4 .. sl*4+3
    int h = sl >> 3;        // head for these 4 features (all 4 in same head)
    float den[4] = {0.f, 0.f, 0.f, 0.f};
    float a0 = 0.f, a1 = 0.f, a2 = 0.f, a3 = 0.f;

    for (int base = 0; base < d; base += 64) {
        int cd = min(64, d - base);
        if (lane < cd) {
            int s = min(max(esrc[off + base + lane], 0), N - 1);
            lsrc[w][lane] = s;
            float4 ssv = *(const float4*)(ssrc + (size_t)s * 4);
            float sv[4] = {ssv.x, ssv.y, ssv.z, ssv.w};
#pragma unroll
            for (int hh = 0; hh < 4; hh++) {
                float v = sv[hh] + st[hh];
                v = v > 0.f ? v : 0.2f * v;
                float ev = __expf(v - M);
                latt[w][lane * 5 + hh] = ev;
                den[hh] += ev;
            }
        }
        // no barrier: intra-wave LDS RAW dependence, ordered by lgkmcnt
        int k = 0;
        // main: 4 pairs = 8 edges per iteration, 4 independent 8B gathers/lane
        for (; k + 8 <= cd; k += 8) {
            int ss[4]; float ee[4]; uint2 vv[4];
#pragma unroll
            for (int u = 0; u < 4; u++) {
                int ke = k + 2 * u + half;
                ss[u] = lsrc[w][ke];
                ee[u] = latt[w][ke * 5 + h];
            }
#pragma unroll
            for (int u = 0; u < 4; u++)
                vv[u] = *(const uint2*)(projb + (size_t)ss[u] * 128 + sl * 4);
#pragma unroll
            for (int u = 0; u < 4; u++) {
                a0 = fmaf(bf2f((unsigned short)(vv[u].x & 0xffffu)), ee[u], a0);
                a1 = fmaf(bf2f((unsigned short)(vv[u].x >> 16)),     ee[u], a1);
                a2 = fmaf(bf2f((unsigned short)(vv[u].y & 0xffffu)), ee[u], a2);
                a3 = fmaf(bf2f((unsigned short)(vv[u].y >> 16)),     ee[u], a3);
            }
        }
        // tail: one pair at a time, mask the dead half on odd counts
        for (; k < cd; k += 2) {
            int ke = k + half;
            bool live = (ke < cd);
            int kidx = live ? ke : k;     // k is always < cd here
            int s = lsrc[w][kidx];
            float ev = live ? latt[w][kidx * 5 + h] : 0.f;
            uint2 v = *(const uint2*)(projb + (size_t)s * 128 + sl * 4);
            a0 = fmaf(bf2f((unsigned short)(v.x & 0xffffu)), ev, a0);
            a1 = fmaf(bf2f((unsigned short)(v.x >> 16)),     ev, a1);
            a2 = fmaf(bf2f((unsigned short)(v.y & 0xffffu)), ev, a2);
            a3 = fmaf(bf2f((unsigned short)(v.y >> 16)),     ev, a3);
        }
    }
    // merge the two half-wave edge subsets
    a0 += __shfl_xor(a0, 32, 64);
    a1 += __shfl_xor(a1, 32, 64);
    a2 += __shfl_xor(a2, 32, 64);
    a3 += __shfl_xor(a3, 32, 64);
    // reduce denominators across all 64 lanes
#pragma unroll
    for (int k = 1; k < 64; k <<= 1)
#pragma unroll
        for (int hh = 0; hh < 4; hh++) den[hh] += __shfl_xor(den[hh], k, 64);
    float inv = 1.0f / (den[h] + 1e-16f);

    if (lane < 32) {
        int j0 = sl * 4;
        float o[4] = {a0 * inv, a1 * inv, a2 * inv, a3 * inv};
#pragma unroll
        for (int j = 0; j < 4; j++) {
            float v = o[j] + ldf(x, n * 128 + j0 + j, f32) + ldf(bias, j0 + j, f32);
            o[j] = v > 0.f ? v : __expf(v) - 1.f;
        }
        *(float4*)(out + (size_t)n * 128 + j0) = make_float4(o[0], o[1], o[2], o[3]);
    }
}

extern "C" void kernel_launch(void* const* d_in, const int* in_sizes, int n_in,
                              void* d_out, int out_size, void* d_ws, size_t ws_size,
                              hipStream_t stream)
{
    const void* x     = d_in[0];
    const int*  ei    = (const int*)d_in[1];
    const void* W     = d_in[2];
    const void* a_src = d_in[3];
    const void* a_trg = d_in[4];
    const void* bias  = d_in[5];
    float* out = (float*)d_out;
    int N = in_sizes[0] / 128;
    int E = N * 16;
    if (in_sizes[1] / 2 < E) E = in_sizes[1] / 2;
    int nbE = (E + 255) / 256;
    int NP1 = N + 1;
    int nbS = (NP1 + 255) / 256;

    char* ws = (char*)d_ws;
    size_t o = 0;
    auto alloc = [&](size_t bytes) {
        size_t r = o;
        o = (o + bytes + 255) & ~(size_t)255;
        return r;
    };
    int* flags = (int*)(ws + alloc(256));
    unsigned short* projb = (unsigned short*)(ws + alloc((size_t)N * 128 * 2));
    float* ssrc  = (float*)(ws + alloc((size_t)N * 4 * 4));
    float* strg  = (float*)(ws + alloc((size_t)N * 4 * 4));
    float* Mval  = (float*)(ws + alloc(256));
    int* counts  = (int*)(ws + alloc((size_t)NP1 * 4));
    int* offsets = (int*)(ws + alloc((size_t)NP1 * 4));
    int* erank   = (int*)(ws + alloc((size_t)E * 4));
    int* esrc    = (int*)(ws + alloc((size_t)E * 4));
    float* blockmax = (float*)(ws + alloc((size_t)nbE * 4));
    int* partials = (int*)(ws + alloc((size_t)nbS * 4));
    unsigned short* WhT = (unsigned short*)(ws + alloc(128 * 128 * 2));
    unsigned short* WlT = (unsigned short*)(ws + alloc(128 * 128 * 2));

    k_det<<<1, 256, 0, stream>>>(x, ei, flags);
    k0_init<<<(N + 256) / 256, 256, 0, stream>>>(counts, N);
    k_conv<<<64, 256, 0, stream>>>(W, flags, WhT, WlT);
    k1_gemm<<<(N + 63) / 64, 256, 0, stream>>>(x, WhT, WlT, a_src, a_trg, flags,
                                               projb, ssrc, strg, N);
    kE_count_max<<<nbE, 256, 0, stream>>>(ei, ssrc, strg, flags, counts, erank,
                                          blockmax, E, N);
    kS1_psum<<<nbS, 256, 0, stream>>>(counts, partials, NP1);
    kS2_scanp<<<1, 256, 0, stream>>>(partials, nbS, blockmax, Mval, nbE);
    kS3_offs<<<nbS, 256, 0, stream>>>(counts, partials, offsets, NP1);
    k2c_scatter<<<nbE, 256, 0, stream>>>(ei, offsets, flags, erank, esrc, E, N);
    k3_agg<<<(N + 3) / 4, 256, 0, stream>>>(offsets, esrc, ssrc, strg, projb, x, bias,
                                            flags, Mval, out, N, E);
}

// Round 5
// 234.646 us; speedup vs baseline: 1.0377x; 1.0377x over previous
//
#include <hip/hip_runtime.h>
#include <stdint.h>

typedef __attribute__((ext_vector_type(8))) short short8;
typedef __attribute__((ext_vector_type(4))) float floatx4;

__device__ inline float bf2f(unsigned short b) {
    unsigned u = ((unsigned)b) << 16;
    return __builtin_bit_cast(float, u);
}
__device__ inline unsigned short f2bf(float f) {
    unsigned u = __builtin_bit_cast(unsigned, f);
    unsigned r = (u + 0x7fffu + ((u >> 16) & 1u)) >> 16;
    return (unsigned short)r;
}
__device__ inline float ldf(const void* p, int i, int f32) {
    return f32 ? ((const float*)p)[i] : bf2f(((const unsigned short*)p)[i]);
}
__device__ inline int lde(const int* ei, int idx, int is64) {
    return is64 ? ei[2 * idx] : ei[idx];
}

// ---- K_det: input dtype layouts (deterministic, every launch) ----
__global__ void k_det(const void* x, const int* ei, int* flags) {
    __shared__ int h1, h2;
    if (threadIdx.x == 0) { h1 = 0; h2 = 0; }
    __syncthreads();
    const unsigned short* xs = (const unsigned short*)x;
    int c1 = 0;
    for (int i = threadIdx.x * 2; i < 65536; i += 512)
        if ((xs[i] & 0x7f80u) == 0x7f80u) c1++;   // fp32 mantissa halves ~1/256; bf16 never
    int c2 = 0;
    for (int i = threadIdx.x * 2 + 1; i < 8192; i += 512)
        if (ei[i] != 0) c2++;                      // int64 high words are 0
    atomicAdd(&h1, c1);
    atomicAdd(&h2, c2);
    __syncthreads();
    if (threadIdx.x == 0) { flags[0] = (h1 >= 8); flags[1] = (h2 < 8); }
}

// ---- K0: zero counts ----
__global__ void k0_init(int* counts, int N) {
    int i = blockIdx.x * blockDim.x + threadIdx.x;
    if (i <= N) counts[i] = 0;
}

// ---- K_conv: W -> transposed bf16 hi/lo (once, not per GEMM block) ----
__global__ __launch_bounds__(256) void k_conv(
    const void* __restrict__ W, const int* __restrict__ flags,
    unsigned short* __restrict__ WhT, unsigned short* __restrict__ WlT)
{
    int f32 = flags[0];
    int idx = blockIdx.x * 256 + threadIdx.x;   // 64 blocks
    if (idx >= 128 * 128) return;
    int n = idx >> 7, k = idx & 127;
    float v = ldf(W, k * 128 + n, f32);
    unsigned short h = f2bf(v);
    WhT[idx] = h;
    WlT[idx] = f2bf(v - bf2f(h));
}

// ---- K1: proj = x@W via bf16x3 MFMA, vectorized staging + fused scores ----
__global__ __launch_bounds__(256) void k1_gemm(
    const void* __restrict__ x, const unsigned short* __restrict__ WhT,
    const unsigned short* __restrict__ WlT, const void* __restrict__ a_src,
    const void* __restrict__ a_trg, const int* __restrict__ flags,
    unsigned short* __restrict__ projb, float* __restrict__ ssrc,
    float* __restrict__ strg, int N)
{
    __shared__ __align__(16) unsigned short WT[128 * 136];
    int t = threadIdx.x;
    int f32 = flags[0];
    for (int i = t; i < 2048; i += 256) {
        int row = i >> 4, ch = (i & 15) * 8;
        *(short8*)&WT[row * 136 + ch] = *(const short8*)&WhT[row * 128 + ch];
    }
    __syncthreads();
    int wave = t >> 6, lane = t & 63;
    int col = lane & 15, quad = lane >> 4;
    int row0 = blockIdx.x * 64 + wave * 16;
    int m = row0 + col;
    if (m >= N) m = N - 1;
    short8 ah[4], al[4];
    if (f32) {
        const float* xf = (const float*)x + (size_t)m * 128 + quad * 8;
#pragma unroll
        for (int kb = 0; kb < 4; kb++) {
            float4 v0 = *(const float4*)(xf + kb * 32);
            float4 v1 = *(const float4*)(xf + kb * 32 + 4);
            float vv[8] = {v0.x, v0.y, v0.z, v0.w, v1.x, v1.y, v1.z, v1.w};
#pragma unroll
            for (int j = 0; j < 8; j++) {
                unsigned short h = f2bf(vv[j]);
                ah[kb][j] = (short)h;
                al[kb][j] = (short)f2bf(vv[j] - bf2f(h));
            }
        }
    } else {
        const unsigned short* xb = (const unsigned short*)x + (size_t)m * 128 + quad * 8;
#pragma unroll
        for (int kb = 0; kb < 4; kb++)
            ah[kb] = *(const short8*)(xb + kb * 32);
    }
    floatx4 acc[8];
#pragma unroll
    for (int c = 0; c < 8; c++) acc[c] = (floatx4){0.f, 0.f, 0.f, 0.f};
#pragma unroll
    for (int c = 0; c < 8; c++) {
        const short8* bp = (const short8*)(&WT[(c * 16 + col) * 136 + quad * 8]);
        short8 b0 = bp[0], b1 = bp[4], b2 = bp[8], b3 = bp[12];
        acc[c] = __builtin_amdgcn_mfma_f32_16x16x32_bf16(ah[0], b0, acc[c], 0, 0, 0);
        acc[c] = __builtin_amdgcn_mfma_f32_16x16x32_bf16(ah[1], b1, acc[c], 0, 0, 0);
        acc[c] = __builtin_amdgcn_mfma_f32_16x16x32_bf16(ah[2], b2, acc[c], 0, 0, 0);
        acc[c] = __builtin_amdgcn_mfma_f32_16x16x32_bf16(ah[3], b3, acc[c], 0, 0, 0);
        if (f32) {
            acc[c] = __builtin_amdgcn_mfma_f32_16x16x32_bf16(al[0], b0, acc[c], 0, 0, 0);
            acc[c] = __builtin_amdgcn_mfma_f32_16x16x32_bf16(al[1], b1, acc[c], 0, 0, 0);
            acc[c] = __builtin_amdgcn_mfma_f32_16x16x32_bf16(al[2], b2, acc[c], 0, 0, 0);
            acc[c] = __builtin_amdgcn_mfma_f32_16x16x32_bf16(al[3], b3, acc[c], 0, 0, 0);
        }
    }
    if (f32) {
        __syncthreads();
        for (int i = t; i < 2048; i += 256) {
            int row = i >> 4, ch = (i & 15) * 8;
            *(short8*)&WT[row * 136 + ch] = *(const short8*)&WlT[row * 128 + ch];
        }
        __syncthreads();
#pragma unroll
        for (int c = 0; c < 8; c++) {
            const short8* bp = (const short8*)(&WT[(c * 16 + col) * 136 + quad * 8]);
            acc[c] = __builtin_amdgcn_mfma_f32_16x16x32_bf16(ah[0], bp[0], acc[c], 0, 0, 0);
            acc[c] = __builtin_amdgcn_mfma_f32_16x16x32_bf16(ah[1], bp[4], acc[c], 0, 0, 0);
            acc[c] = __builtin_amdgcn_mfma_f32_16x16x32_bf16(ah[2], bp[8], acc[c], 0, 0, 0);
            acc[c] = __builtin_amdgcn_mfma_f32_16x16x32_bf16(ah[3], bp[12], acc[c], 0, 0, 0);
        }
    }
#pragma unroll
    for (int r = 0; r < 4; r++) {
        int row = row0 + quad * 4 + r;
        if (row < N) {
#pragma unroll
            for (int c = 0; c < 8; c++)
                projb[(size_t)row * 128 + c * 16 + col] = f2bf(acc[c][r]);
        }
    }
    float asv[8], atv[8];
#pragma unroll
    for (int c = 0; c < 8; c++) {
        int j = c * 16 + col;
        asv[c] = ldf(a_src, j, f32);
        atv[c] = ldf(a_trg, j, f32);
    }
#pragma unroll
    for (int r = 0; r < 4; r++) {
        int row = row0 + quad * 4 + r;
        float ps[4] = {0.f, 0.f, 0.f, 0.f}, pt[4] = {0.f, 0.f, 0.f, 0.f};
#pragma unroll
        for (int c = 0; c < 8; c++) {
            int h = c >> 1;
            ps[h] += acc[c][r] * asv[c];
            pt[h] += acc[c][r] * atv[c];
        }
#pragma unroll
        for (int k = 1; k < 16; k <<= 1) {
#pragma unroll
            for (int h = 0; h < 4; h++) {
                ps[h] += __shfl_xor(ps[h], k, 16);
                pt[h] += __shfl_xor(pt[h], k, 16);
            }
        }
        if (col == 0 && row < N) {
#pragma unroll
            for (int h = 0; h < 4; h++) {
                ssrc[(size_t)row * 4 + h] = ps[h];
                strg[(size_t)row * 4 + h] = pt[h];
            }
        }
    }
}

__device__ inline void edge_scores(const float* ssrc, const float* strg,
                                   int src, int trg, float* v) {
    float4 a = *(const float4*)(ssrc + (size_t)src * 4);
    float4 b = *(const float4*)(strg + (size_t)trg * 4);
    v[0] = a.x + b.x; v[1] = a.y + b.y; v[2] = a.z + b.z; v[3] = a.w + b.w;
#pragma unroll
    for (int h = 0; h < 4; h++) v[h] = v[h] > 0.f ? v[h] : 0.2f * v[h];
}

// ---- KE: in-degree histogram + per-block TRUE edge max.
//      The atomic's return value IS the within-segment rank (saves k2c's atomic).
//      NOTE: the true edge max is semantically required — it participates in the
//      reference's (denom + 1e-16) epsilon floor; an upper bound is NOT valid. ----
__global__ __launch_bounds__(256) void kE_count_max(
    const int* __restrict__ ei, const float* __restrict__ ssrc,
    const float* __restrict__ strg, const int* __restrict__ flags,
    int* __restrict__ counts, int* __restrict__ erank,
    float* __restrict__ blockmax, int E, int N)
{
    int e64 = flags[1];
    int e = blockIdx.x * 256 + threadIdx.x;
    float m = -3.0e38f;
    if (e < E) {
        int src = min(max(lde(ei, e, e64), 0), N - 1);
        int trg = min(max(lde(ei, E + e, e64), 0), N - 1);
        erank[e] = atomicAdd(&counts[trg], 1);
        float v[4];
        edge_scores(ssrc, strg, src, trg, v);
        m = fmaxf(fmaxf(v[0], v[1]), fmaxf(v[2], v[3]));
    }
#pragma unroll
    for (int k = 1; k < 64; k <<= 1) m = fmaxf(m, __shfl_xor(m, k, 64));
    __shared__ float wm[4];
    if ((threadIdx.x & 63) == 0) wm[threadIdx.x >> 6] = m;
    __syncthreads();
    if (threadIdx.x == 0)
        blockmax[blockIdx.x] = fmaxf(fmaxf(wm[0], wm[1]), fmaxf(wm[2], wm[3]));
}

// ---- S1: per-block sums of counts (coalesced) ----
__global__ __launch_bounds__(256) void kS1_psum(
    const int* __restrict__ counts, int* __restrict__ partials, int NP1)
{
    int idx = blockIdx.x * 256 + threadIdx.x;
    int v = (idx < NP1) ? counts[idx] : 0;
#pragma unroll
    for (int k = 1; k < 64; k <<= 1) v += __shfl_xor(v, k, 64);
    __shared__ int wsum[4];
    if ((threadIdx.x & 63) == 0) wsum[threadIdx.x >> 6] = v;
    __syncthreads();
    if (threadIdx.x == 0)
        partials[blockIdx.x] = wsum[0] + wsum[1] + wsum[2] + wsum[3];
}

// ---- S2: exclusive scan of partials (<=256) + Mval reduction (1 block) ----
__global__ __launch_bounds__(256) void kS2_scanp(
    int* __restrict__ partials, int nb,
    const float* __restrict__ blockmax, float* __restrict__ Mval, int nbm)
{
    int t = threadIdx.x;
    if (nb <= 256) {
        __shared__ int lds[256];
        int v = (t < nb) ? partials[t] : 0;
        lds[t] = v;
        __syncthreads();
        int incl = v;
        for (int st = 1; st < 256; st <<= 1) {
            int add = (t >= st) ? lds[t - st] : 0;
            __syncthreads();
            incl += add;
            lds[t] = incl;
            __syncthreads();
        }
        if (t < nb) partials[t] = incl - v;
    } else if (t == 0) {
        int run = 0;
        for (int i = 0; i < nb; i++) { int c = partials[i]; partials[i] = run; run += c; }
    }
    __syncthreads();
    float m = -3.0e38f;
    for (int i = t; i < nbm; i += 256) m = fmaxf(m, blockmax[i]);
#pragma unroll
    for (int k = 1; k < 64; k <<= 1) m = fmaxf(m, __shfl_xor(m, k, 64));
    __shared__ float wm[4];
    if ((t & 63) == 0) wm[t >> 6] = m;
    __syncthreads();
    if (t == 0) *Mval = fmaxf(fmaxf(wm[0], wm[1]), fmaxf(wm[2], wm[3]));
}

// ---- S3: per-block exclusive scan + base -> offsets (coalesced) ----
__global__ __launch_bounds__(256) void kS3_offs(
    const int* __restrict__ counts, const int* __restrict__ partials,
    int* __restrict__ offsets, int NP1)
{
    int t = threadIdx.x;
    int idx = blockIdx.x * 256 + t;
    int v = (idx < NP1) ? counts[idx] : 0;
    __shared__ int lds[256];
    lds[t] = v;
    __syncthreads();
    int incl = v;
    for (int st = 1; st < 256; st <<= 1) {
        int add = (t >= st) ? lds[t - st] : 0;
        __syncthreads();
        incl += add;
        lds[t] = incl;
        __syncthreads();
    }
    if (idx < NP1) offsets[idx] = partials[blockIdx.x] + incl - v;
}

// ---- K2c: fused CSR scatter. M is available here (runs after kS2), so compute
//      the exp'd attention weights NOW and scatter one 16 B record per edge:
//      {src, bf16(e0,e1), bf16(e2,e3), 0}. This removes the random ssrc gather
//      and the expf from k3's serial staging chain; the gathers here are
//      L2-resident (ssrc/strg = 800 KB each) and overlap the scatter stores. ----
__global__ __launch_bounds__(256) void k2c_scatter(
    const int* __restrict__ ei, const int* __restrict__ offsets,
    const int* __restrict__ flags, const int* __restrict__ erank,
    const float* __restrict__ ssrc, const float* __restrict__ strg,
    const float* __restrict__ Mval, uint4* __restrict__ erec, int E, int N)
{
    int e64 = flags[1];
    int e = blockIdx.x * 256 + threadIdx.x;
    if (e >= E) return;
    int src = min(max(lde(ei, e, e64), 0), N - 1);
    int trg = min(max(lde(ei, E + e, e64), 0), N - 1);
    int pos = offsets[trg] + erank[e];
    float M = *Mval;
    float v[4];
    edge_scores(ssrc, strg, src, trg, v);
    unsigned e01 = (unsigned)f2bf(__expf(v[0] - M)) |
                   ((unsigned)f2bf(__expf(v[1] - M)) << 16);
    unsigned e23 = (unsigned)f2bf(__expf(v[2] - M)) |
                   ((unsigned)f2bf(__expf(v[3] - M)) << 16);
    if (pos >= 0 && pos < E)
        erec[pos] = make_uint4((unsigned)src, e01, e23, 0u);
}

// ---- K3: aggregation only. Staging = ONE coalesced 16 B/lane record load
//      (no random gather, no expf in the chain). 2 edges per wave-iteration,
//      8 B projb gather per lane, unroll-4 for MLP. Wave-independent. ----
__global__ __launch_bounds__(256) void k3_agg(
    const int* __restrict__ offsets, const uint4* __restrict__ erec,
    const unsigned short* __restrict__ projb, const void* __restrict__ x,
    const void* __restrict__ bias, const int* __restrict__ flags,
    float* __restrict__ out, int N, int E)
{
    int w = threadIdx.x >> 6;
    int lane = threadIdx.x & 63;
    int n = blockIdx.x * 4 + w;
    int f32 = flags[0];
    if (n >= N) return;
    int off = offsets[n];
    int d = offsets[n + 1] - off;
    d = max(0, min(d, E));

    __shared__ int lsrc[4][64];
    __shared__ unsigned le[4][128];   // 2 packed-bf16 words per edge

    int half = lane >> 5;   // which edge of the current pair this lane serves
    int sl = lane & 31;     // feature group: features sl*4 .. sl*4+3
    int h = sl >> 3;        // head for these 4 features
    int hw = h >> 1;        // which packed word holds this head
    int hs = (h & 1) << 4;  // shift within the word
    float den[4] = {0.f, 0.f, 0.f, 0.f};
    float a0 = 0.f, a1 = 0.f, a2 = 0.f, a3 = 0.f;

    for (int base = 0; base < d; base += 64) {
        int cd = min(64, d - base);
        if (lane < cd) {
            uint4 r = erec[off + base + lane];
            lsrc[w][lane] = min(max((int)r.x, 0), N - 1);
            le[w][lane * 2] = r.y;
            le[w][lane * 2 + 1] = r.z;
            den[0] += bf2f((unsigned short)(r.y & 0xffffu));
            den[1] += bf2f((unsigned short)(r.y >> 16));
            den[2] += bf2f((unsigned short)(r.z & 0xffffu));
            den[3] += bf2f((unsigned short)(r.z >> 16));
        }
        // no barrier: intra-wave LDS RAW dependence, ordered by lgkmcnt
        int k = 0;
        for (; k + 8 <= cd; k += 8) {
            int ss[4]; float ee[4]; uint2 vv[4];
#pragma unroll
            for (int u = 0; u < 4; u++) {
                int ke = k + 2 * u + half;
                ss[u] = lsrc[w][ke];
                unsigned wd = le[w][ke * 2 + hw];
                ee[u] = bf2f((unsigned short)((wd >> hs) & 0xffffu));
            }
#pragma unroll
            for (int u = 0; u < 4; u++)
                vv[u] = *(const uint2*)(projb + (size_t)ss[u] * 128 + sl * 4);
#pragma unroll
            for (int u = 0; u < 4; u++) {
                a0 = fmaf(bf2f((unsigned short)(vv[u].x & 0xffffu)), ee[u], a0);
                a1 = fmaf(bf2f((unsigned short)(vv[u].x >> 16)),     ee[u], a1);
                a2 = fmaf(bf2f((unsigned short)(vv[u].y & 0xffffu)), ee[u], a2);
                a3 = fmaf(bf2f((unsigned short)(vv[u].y >> 16)),     ee[u], a3);
            }
        }
        for (; k < cd; k += 2) {
            int ke = k + half;
            bool live = (ke < cd);
            int kidx = live ? ke : k;
            int s = lsrc[w][kidx];
            unsigned wd = le[w][kidx * 2 + hw];
            float ev = live ? bf2f((unsigned short)((wd >> hs) & 0xffffu)) : 0.f;
            uint2 v = *(const uint2*)(projb + (size_t)s * 128 + sl * 4);
            a0 = fmaf(bf2f((unsigned short)(v.x & 0xffffu)), ev, a0);
            a1 = fmaf(bf2f((unsigned short)(v.x >> 16)),     ev, a1);
            a2 = fmaf(bf2f((unsigned short)(v.y & 0xffffu)), ev, a2);
            a3 = fmaf(bf2f((unsigned short)(v.y >> 16)),     ev, a3);
        }
    }
    // merge the two half-wave edge subsets
    a0 += __shfl_xor(a0, 32, 64);
    a1 += __shfl_xor(a1, 32, 64);
    a2 += __shfl_xor(a2, 32, 64);
    a3 += __shfl_xor(a3, 32, 64);
    // reduce denominators across all 64 lanes
#pragma unroll
    for (int k = 1; k < 64; k <<= 1)
#pragma unroll
        for (int hh = 0; hh < 4; hh++) den[hh] += __shfl_xor(den[hh], k, 64);
    float inv = 1.0f / (den[h] + 1e-16f);

    if (lane < 32) {
        int j0 = sl * 4;
        float o[4] = {a0 * inv, a1 * inv, a2 * inv, a3 * inv};
#pragma unroll
        for (int j = 0; j < 4; j++) {
            float v = o[j] + ldf(x, n * 128 + j0 + j, f32) + ldf(bias, j0 + j, f32);
            o[j] = v > 0.f ? v : __expf(v) - 1.f;
        }
        *(float4*)(out + (size_t)n * 128 + j0) = make_float4(o[0], o[1], o[2], o[3]);
    }
}

extern "C" void kernel_launch(void* const* d_in, const int* in_sizes, int n_in,
                              void* d_out, int out_size, void* d_ws, size_t ws_size,
                              hipStream_t stream)
{
    const void* x     = d_in[0];
    const int*  ei    = (const int*)d_in[1];
    const void* W     = d_in[2];
    const void* a_src = d_in[3];
    const void* a_trg = d_in[4];
    const void* bias  = d_in[5];
    float* out = (float*)d_out;
    int N = in_sizes[0] / 128;
    int E = N * 16;
    if (in_sizes[1] / 2 < E) E = in_sizes[1] / 2;
    int nbE = (E + 255) / 256;
    int NP1 = N + 1;
    int nbS = (NP1 + 255) / 256;

    char* ws = (char*)d_ws;
    size_t o = 0;
    auto alloc = [&](size_t bytes) {
        size_t r = o;
        o = (o + bytes + 255) & ~(size_t)255;
        return r;
    };
    int* flags = (int*)(ws + alloc(256));
    unsigned short* projb = (unsigned short*)(ws + alloc((size_t)N * 128 * 2));
    float* ssrc  = (float*)(ws + alloc((size_t)N * 4 * 4));
    float* strg  = (float*)(ws + alloc((size_t)N * 4 * 4));
    float* Mval  = (float*)(ws + alloc(256));
    int* counts  = (int*)(ws + alloc((size_t)NP1 * 4));
    int* offsets = (int*)(ws + alloc((size_t)NP1 * 4));
    int* erank   = (int*)(ws + alloc((size_t)E * 4));
    uint4* erec  = (uint4*)(ws + alloc((size_t)E * 16));
    float* blockmax = (float*)(ws + alloc((size_t)nbE * 4));
    int* partials = (int*)(ws + alloc((size_t)nbS * 4));
    unsigned short* WhT = (unsigned short*)(ws + alloc(128 * 128 * 2));
    unsigned short* WlT = (unsigned short*)(ws + alloc(128 * 128 * 2));

    k_det<<<1, 256, 0, stream>>>(x, ei, flags);
    k0_init<<<(N + 256) / 256, 256, 0, stream>>>(counts, N);
    k_conv<<<64, 256, 0, stream>>>(W, flags, WhT, WlT);
    k1_gemm<<<(N + 63) / 64, 256, 0, stream>>>(x, WhT, WlT, a_src, a_trg, flags,
                                               projb, ssrc, strg, N);
    kE_count_max<<<nbE, 256, 0, stream>>>(ei, ssrc, strg, flags, counts, erank,
                                          blockmax, E, N);
    kS1_psum<<<nbS, 256, 0, stream>>>(counts, partials, NP1);
    kS2_scanp<<<1, 256, 0, stream>>>(partials, nbS, blockmax, Mval, nbE);
    kS3_offs<<<nbS, 256, 0, stream>>>(counts, partials, offsets, NP1);
    k2c_scatter<<<nbE, 256, 0, stream>>>(ei, offsets, flags, erank, ssrc, strg,
                                         Mval, erec, E, N);
    k3_agg<<<(N + 3) / 4, 256, 0, stream>>>(offsets, erec, projb, x, bias,
                                            flags, out, N, E);
}

// Round 6
// 226.098 us; speedup vs baseline: 1.0769x; 1.0378x over previous
//
#include <hip/hip_runtime.h>
#include <stdint.h>

typedef __attribute__((ext_vector_type(8))) short short8;
typedef __attribute__((ext_vector_type(4))) float floatx4;

__device__ inline float bf2f(unsigned short b) {
    unsigned u = ((unsigned)b) << 16;
    return __builtin_bit_cast(float, u);
}
__device__ inline unsigned short f2bf(float f) {
    unsigned u = __builtin_bit_cast(unsigned, f);
    unsigned r = (u + 0x7fffu + ((u >> 16) & 1u)) >> 16;
    return (unsigned short)r;
}
__device__ inline float ldf(const void* p, int i, int f32) {
    return f32 ? ((const float*)p)[i] : bf2f(((const unsigned short*)p)[i]);
}
__device__ inline int lde(const int* ei, int idx, int is64) {
    return is64 ? ei[2 * idx] : ei[idx];
}

// ---- K_pre: fused {dtype det | W->bf16 hi/lo transpose | zero counts}.
//      Block 0: x/ei dtype flags. Blocks 1..64: W transpose, self-detecting
//      W's dtype from W's own bits (bf16 finite values never have exp==0xFF;
//      fp32 mantissa low-halves hit the pattern ~1/256 -> 8192 samples,
//      threshold 8, deterministic and identical for every block).
//      Blocks 65+: zero counts. ----
__global__ __launch_bounds__(256) void k_pre(
    const void* __restrict__ x, const int* __restrict__ ei,
    const void* __restrict__ W, int* __restrict__ flags,
    unsigned short* __restrict__ WhT, unsigned short* __restrict__ WlT,
    int* __restrict__ counts, int N)
{
    int b = blockIdx.x;
    int t = threadIdx.x;
    if (b == 0) {
        __shared__ int h1, h2;
        if (t == 0) { h1 = 0; h2 = 0; }
        __syncthreads();
        const unsigned short* xs = (const unsigned short*)x;
        int c1 = 0;
        for (int i = t * 2; i < 65536; i += 512)
            if ((xs[i] & 0x7f80u) == 0x7f80u) c1++;   // fp32 mantissa halves ~1/256; bf16 never
        int c2 = 0;
        for (int i = t * 2 + 1; i < 8192; i += 512)
            if (ei[i] != 0) c2++;                      // int64 high words are 0
        atomicAdd(&h1, c1);
        atomicAdd(&h2, c2);
        __syncthreads();
        if (t == 0) { flags[0] = (h1 >= 8); flags[1] = (h2 < 8); }
    } else if (b <= 64) {
        __shared__ int wcnt;
        if (t == 0) wcnt = 0;
        __syncthreads();
        const unsigned short* wsamp = (const unsigned short*)W;
        int c = 0;
        for (int i = t * 2; i < 16384; i += 512)
            if ((wsamp[i] & 0x7f80u) == 0x7f80u) c++;
        atomicAdd(&wcnt, c);
        __syncthreads();
        int f32 = (wcnt >= 8);
        int idx = (b - 1) * 256 + t;
        int n = idx >> 7, k = idx & 127;
        float v = ldf(W, k * 128 + n, f32);
        unsigned short h = f2bf(v);
        WhT[idx] = h;
        WlT[idx] = f2bf(v - bf2f(h));
    } else {
        int idx = (b - 65) * 256 + t;
        if (idx <= N) counts[idx] = 0;
    }
}

// ---- K1: proj = x@W via bf16x3 MFMA, vectorized staging + fused scores ----
__global__ __launch_bounds__(256) void k1_gemm(
    const void* __restrict__ x, const unsigned short* __restrict__ WhT,
    const unsigned short* __restrict__ WlT, const void* __restrict__ a_src,
    const void* __restrict__ a_trg, const int* __restrict__ flags,
    unsigned short* __restrict__ projb, float* __restrict__ ssrc,
    float* __restrict__ strg, int N)
{
    __shared__ __align__(16) unsigned short WT[128 * 136];
    int t = threadIdx.x;
    int f32 = flags[0];
    for (int i = t; i < 2048; i += 256) {
        int row = i >> 4, ch = (i & 15) * 8;
        *(short8*)&WT[row * 136 + ch] = *(const short8*)&WhT[row * 128 + ch];
    }
    __syncthreads();
    int wave = t >> 6, lane = t & 63;
    int col = lane & 15, quad = lane >> 4;
    int row0 = blockIdx.x * 64 + wave * 16;
    int m = row0 + col;
    if (m >= N) m = N - 1;
    short8 ah[4], al[4];
    if (f32) {
        const float* xf = (const float*)x + (size_t)m * 128 + quad * 8;
#pragma unroll
        for (int kb = 0; kb < 4; kb++) {
            float4 v0 = *(const float4*)(xf + kb * 32);
            float4 v1 = *(const float4*)(xf + kb * 32 + 4);
            float vv[8] = {v0.x, v0.y, v0.z, v0.w, v1.x, v1.y, v1.z, v1.w};
#pragma unroll
            for (int j = 0; j < 8; j++) {
                unsigned short h = f2bf(vv[j]);
                ah[kb][j] = (short)h;
                al[kb][j] = (short)f2bf(vv[j] - bf2f(h));
            }
        }
    } else {
        const unsigned short* xb = (const unsigned short*)x + (size_t)m * 128 + quad * 8;
#pragma unroll
        for (int kb = 0; kb < 4; kb++)
            ah[kb] = *(const short8*)(xb + kb * 32);
    }
    floatx4 acc[8];
#pragma unroll
    for (int c = 0; c < 8; c++) acc[c] = (floatx4){0.f, 0.f, 0.f, 0.f};
#pragma unroll
    for (int c = 0; c < 8; c++) {
        const short8* bp = (const short8*)(&WT[(c * 16 + col) * 136 + quad * 8]);
        short8 b0 = bp[0], b1 = bp[4], b2 = bp[8], b3 = bp[12];
        acc[c] = __builtin_amdgcn_mfma_f32_16x16x32_bf16(ah[0], b0, acc[c], 0, 0, 0);
        acc[c] = __builtin_amdgcn_mfma_f32_16x16x32_bf16(ah[1], b1, acc[c], 0, 0, 0);
        acc[c] = __builtin_amdgcn_mfma_f32_16x16x32_bf16(ah[2], b2, acc[c], 0, 0, 0);
        acc[c] = __builtin_amdgcn_mfma_f32_16x16x32_bf16(ah[3], b3, acc[c], 0, 0, 0);
        if (f32) {
            acc[c] = __builtin_amdgcn_mfma_f32_16x16x32_bf16(al[0], b0, acc[c], 0, 0, 0);
            acc[c] = __builtin_amdgcn_mfma_f32_16x16x32_bf16(al[1], b1, acc[c], 0, 0, 0);
            acc[c] = __builtin_amdgcn_mfma_f32_16x16x32_bf16(al[2], b2, acc[c], 0, 0, 0);
            acc[c] = __builtin_amdgcn_mfma_f32_16x16x32_bf16(al[3], b3, acc[c], 0, 0, 0);
        }
    }
    if (f32) {
        __syncthreads();
        for (int i = t; i < 2048; i += 256) {
            int row = i >> 4, ch = (i & 15) * 8;
            *(short8*)&WT[row * 136 + ch] = *(const short8*)&WlT[row * 128 + ch];
        }
        __syncthreads();
#pragma unroll
        for (int c = 0; c < 8; c++) {
            const short8* bp = (const short8*)(&WT[(c * 16 + col) * 136 + quad * 8]);
            acc[c] = __builtin_amdgcn_mfma_f32_16x16x32_bf16(ah[0], bp[0], acc[c], 0, 0, 0);
            acc[c] = __builtin_amdgcn_mfma_f32_16x16x32_bf16(ah[1], bp[4], acc[c], 0, 0, 0);
            acc[c] = __builtin_amdgcn_mfma_f32_16x16x32_bf16(ah[2], bp[8], acc[c], 0, 0, 0);
            acc[c] = __builtin_amdgcn_mfma_f32_16x16x32_bf16(ah[3], bp[12], acc[c], 0, 0, 0);
        }
    }
#pragma unroll
    for (int r = 0; r < 4; r++) {
        int row = row0 + quad * 4 + r;
        if (row < N) {
#pragma unroll
            for (int c = 0; c < 8; c++)
                projb[(size_t)row * 128 + c * 16 + col] = f2bf(acc[c][r]);
        }
    }
    float asv[8], atv[8];
#pragma unroll
    for (int c = 0; c < 8; c++) {
        int j = c * 16 + col;
        asv[c] = ldf(a_src, j, f32);
        atv[c] = ldf(a_trg, j, f32);
    }
#pragma unroll
    for (int r = 0; r < 4; r++) {
        int row = row0 + quad * 4 + r;
        float ps[4] = {0.f, 0.f, 0.f, 0.f}, pt[4] = {0.f, 0.f, 0.f, 0.f};
#pragma unroll
        for (int c = 0; c < 8; c++) {
            int h = c >> 1;
            ps[h] += acc[c][r] * asv[c];
            pt[h] += acc[c][r] * atv[c];
        }
#pragma unroll
        for (int k = 1; k < 16; k <<= 1) {
#pragma unroll
            for (int h = 0; h < 4; h++) {
                ps[h] += __shfl_xor(ps[h], k, 16);
                pt[h] += __shfl_xor(pt[h], k, 16);
            }
        }
        if (col == 0 && row < N) {
#pragma unroll
            for (int h = 0; h < 4; h++) {
                ssrc[(size_t)row * 4 + h] = ps[h];
                strg[(size_t)row * 4 + h] = pt[h];
            }
        }
    }
}

__device__ inline void edge_scores(const float* ssrc, const float* strg,
                                   int src, int trg, float* v) {
    float4 a = *(const float4*)(ssrc + (size_t)src * 4);
    float4 b = *(const float4*)(strg + (size_t)trg * 4);
    v[0] = a.x + b.x; v[1] = a.y + b.y; v[2] = a.z + b.z; v[3] = a.w + b.w;
#pragma unroll
    for (int h = 0; h < 4; h++) v[h] = v[h] > 0.f ? v[h] : 0.2f * v[h];
}

// ---- KE: single edge-materialization pass.
//      - in-degree histogram; atomic return value IS the within-segment rank
//      - leaky scores v[4] computed ONCE, persisted as f32 (bit-identical later)
//      - packed records {src,trg,rank} + {v0..v3} for k2c (no ei re-read there)
//      - per-block TRUE edge max (semantically required: epsilon floor) ----
__global__ __launch_bounds__(256) void kE_count_max(
    const int* __restrict__ ei, const float* __restrict__ ssrc,
    const float* __restrict__ strg, const int* __restrict__ flags,
    int* __restrict__ counts, uint4* __restrict__ epackI,
    float4* __restrict__ epackV, float* __restrict__ blockmax, int E, int N)
{
    int e64 = flags[1];
    int e = blockIdx.x * 256 + threadIdx.x;
    float m = -3.0e38f;
    if (e < E) {
        int src = min(max(lde(ei, e, e64), 0), N - 1);
        int trg = min(max(lde(ei, E + e, e64), 0), N - 1);
        int rank = atomicAdd(&counts[trg], 1);
        float v[4];
        edge_scores(ssrc, strg, src, trg, v);
        m = fmaxf(fmaxf(v[0], v[1]), fmaxf(v[2], v[3]));
        epackI[e] = make_uint4((unsigned)src, (unsigned)trg, (unsigned)rank, 0u);
        epackV[e] = make_float4(v[0], v[1], v[2], v[3]);
    }
#pragma unroll
    for (int k = 1; k < 64; k <<= 1) m = fmaxf(m, __shfl_xor(m, k, 64));
    __shared__ float wm[4];
    if ((threadIdx.x & 63) == 0) wm[threadIdx.x >> 6] = m;
    __syncthreads();
    if (threadIdx.x == 0)
        blockmax[blockIdx.x] = fmaxf(fmaxf(wm[0], wm[1]), fmaxf(wm[2], wm[3]));
}

// ---- S1: per-block sums of counts (coalesced) ----
__global__ __launch_bounds__(256) void kS1_psum(
    const int* __restrict__ counts, int* __restrict__ partials, int NP1)
{
    int idx = blockIdx.x * 256 + threadIdx.x;
    int v = (idx < NP1) ? counts[idx] : 0;
#pragma unroll
    for (int k = 1; k < 64; k <<= 1) v += __shfl_xor(v, k, 64);
    __shared__ int wsum[4];
    if ((threadIdx.x & 63) == 0) wsum[threadIdx.x >> 6] = v;
    __syncthreads();
    if (threadIdx.x == 0)
        partials[blockIdx.x] = wsum[0] + wsum[1] + wsum[2] + wsum[3];
}

// ---- S2: exclusive scan of partials (<=256) + Mval reduction (1 block) ----
__global__ __launch_bounds__(256) void kS2_scanp(
    int* __restrict__ partials, int nb,
    const float* __restrict__ blockmax, float* __restrict__ Mval, int nbm)
{
    int t = threadIdx.x;
    if (nb <= 256) {
        __shared__ int lds[256];
        int v = (t < nb) ? partials[t] : 0;
        lds[t] = v;
        __syncthreads();
        int incl = v;
        for (int st = 1; st < 256; st <<= 1) {
            int add = (t >= st) ? lds[t - st] : 0;
            __syncthreads();
            incl += add;
            lds[t] = incl;
            __syncthreads();
        }
        if (t < nb) partials[t] = incl - v;
    } else if (t == 0) {
        int run = 0;
        for (int i = 0; i < nb; i++) { int c = partials[i]; partials[i] = run; run += c; }
    }
    __syncthreads();
    float m = -3.0e38f;
    for (int i = t; i < nbm; i += 256) m = fmaxf(m, blockmax[i]);
#pragma unroll
    for (int k = 1; k < 64; k <<= 1) m = fmaxf(m, __shfl_xor(m, k, 64));
    __shared__ float wm[4];
    if ((t & 63) == 0) wm[t >> 6] = m;
    __syncthreads();
    if (t == 0) *Mval = fmaxf(fmaxf(wm[0], wm[1]), fmaxf(wm[2], wm[3]));
}

// ---- S3: per-block exclusive scan + base -> offsets (coalesced) ----
__global__ __launch_bounds__(256) void kS3_offs(
    const int* __restrict__ counts, const int* __restrict__ partials,
    int* __restrict__ offsets, int NP1)
{
    int t = threadIdx.x;
    int idx = blockIdx.x * 256 + t;
    int v = (idx < NP1) ? counts[idx] : 0;
    __shared__ int lds[256];
    lds[t] = v;
    __syncthreads();
    int incl = v;
    for (int st = 1; st < 256; st <<= 1) {
        int add = (t >= st) ? lds[t - st] : 0;
        __syncthreads();
        incl += add;
        lds[t] = incl;
        __syncthreads();
    }
    if (idx < NP1) offsets[idx] = partials[blockIdx.x] + incl - v;
}

// ---- K2c: thin exp + CSR scatter. Reads ONLY the packed records (fully
//      coalesced), one random offsets lookup (L2), scatters the 16 B erec
//      {src, bf16(e0,e1), bf16(e2,e3)}. No ei, no gathers, no atomics. ----
__global__ __launch_bounds__(256) void k2c_scatter(
    const uint4* __restrict__ epackI, const float4* __restrict__ epackV,
    const int* __restrict__ offsets, const float* __restrict__ Mval,
    uint4* __restrict__ erec, int E)
{
    int e = blockIdx.x * 256 + threadIdx.x;
    if (e >= E) return;
    uint4 pi = epackI[e];
    float4 pv = epackV[e];
    float M = *Mval;
    int pos = offsets[pi.y] + (int)pi.z;
    unsigned e01 = (unsigned)f2bf(__expf(pv.x - M)) |
                   ((unsigned)f2bf(__expf(pv.y - M)) << 16);
    unsigned e23 = (unsigned)f2bf(__expf(pv.z - M)) |
                   ((unsigned)f2bf(__expf(pv.w - M)) << 16);
    if (pos >= 0 && pos < E)
        erec[pos] = make_uint4(pi.x, e01, e23, 0u);
}

// ---- K3: aggregation only. Staging = ONE coalesced 16 B/lane record load
//      (no random gather, no expf in the chain). 2 edges per wave-iteration,
//      8 B projb gather per lane, unroll-4 for MLP. Wave-independent. ----
__global__ __launch_bounds__(256) void k3_agg(
    const int* __restrict__ offsets, const uint4* __restrict__ erec,
    const unsigned short* __restrict__ projb, const void* __restrict__ x,
    const void* __restrict__ bias, const int* __restrict__ flags,
    float* __restrict__ out, int N, int E)
{
    int w = threadIdx.x >> 6;
    int lane = threadIdx.x & 63;
    int n = blockIdx.x * 4 + w;
    int f32 = flags[0];
    if (n >= N) return;
    int off = offsets[n];
    int d = offsets[n + 1] - off;
    d = max(0, min(d, E));

    __shared__ int lsrc[4][64];
    __shared__ unsigned le[4][128];   // 2 packed-bf16 words per edge

    int half = lane >> 5;   // which edge of the current pair this lane serves
    int sl = lane & 31;     // feature group: features sl*4 .. sl*4+3
    int h = sl >> 3;        // head for these 4 features
    int hw = h >> 1;        // which packed word holds this head
    int hs = (h & 1) << 4;  // shift within the word
    float den[4] = {0.f, 0.f, 0.f, 0.f};
    float a0 = 0.f, a1 = 0.f, a2 = 0.f, a3 = 0.f;

    for (int base = 0; base < d; base += 64) {
        int cd = min(64, d - base);
        if (lane < cd) {
            uint4 r = erec[off + base + lane];
            lsrc[w][lane] = min(max((int)r.x, 0), N - 1);
            le[w][lane * 2] = r.y;
            le[w][lane * 2 + 1] = r.z;
            den[0] += bf2f((unsigned short)(r.y & 0xffffu));
            den[1] += bf2f((unsigned short)(r.y >> 16));
            den[2] += bf2f((unsigned short)(r.z & 0xffffu));
            den[3] += bf2f((unsigned short)(r.z >> 16));
        }
        // no barrier: intra-wave LDS RAW dependence, ordered by lgkmcnt
        int k = 0;
        for (; k + 8 <= cd; k += 8) {
            int ss[4]; float ee[4]; uint2 vv[4];
#pragma unroll
            for (int u = 0; u < 4; u++) {
                int ke = k + 2 * u + half;
                ss[u] = lsrc[w][ke];
                unsigned wd = le[w][ke * 2 + hw];
                ee[u] = bf2f((unsigned short)((wd >> hs) & 0xffffu));
            }
#pragma unroll
            for (int u = 0; u < 4; u++)
                vv[u] = *(const uint2*)(projb + (size_t)ss[u] * 128 + sl * 4);
#pragma unroll
            for (int u = 0; u < 4; u++) {
                a0 = fmaf(bf2f((unsigned short)(vv[u].x & 0xffffu)), ee[u], a0);
                a1 = fmaf(bf2f((unsigned short)(vv[u].x >> 16)),     ee[u], a1);
                a2 = fmaf(bf2f((unsigned short)(vv[u].y & 0xffffu)), ee[u], a2);
                a3 = fmaf(bf2f((unsigned short)(vv[u].y >> 16)),     ee[u], a3);
            }
        }
        for (; k < cd; k += 2) {
            int ke = k + half;
            bool live = (ke < cd);
            int kidx = live ? ke : k;
            int s = lsrc[w][kidx];
            unsigned wd = le[w][kidx * 2 + hw];
            float ev = live ? bf2f((unsigned short)((wd >> hs) & 0xffffu)) : 0.f;
            uint2 v = *(const uint2*)(projb + (size_t)s * 128 + sl * 4);
            a0 = fmaf(bf2f((unsigned short)(v.x & 0xffffu)), ev, a0);
            a1 = fmaf(bf2f((unsigned short)(v.x >> 16)),     ev, a1);
            a2 = fmaf(bf2f((unsigned short)(v.y & 0xffffu)), ev, a2);
            a3 = fmaf(bf2f((unsigned short)(v.y >> 16)),     ev, a3);
        }
    }
    // merge the two half-wave edge subsets
    a0 += __shfl_xor(a0, 32, 64);
    a1 += __shfl_xor(a1, 32, 64);
    a2 += __shfl_xor(a2, 32, 64);
    a3 += __shfl_xor(a3, 32, 64);
    // reduce denominators across all 64 lanes
#pragma unroll
    for (int k = 1; k < 64; k <<= 1)
#pragma unroll
        for (int hh = 0; hh < 4; hh++) den[hh] += __shfl_xor(den[hh], k, 64);
    float inv = 1.0f / (den[h] + 1e-16f);

    if (lane < 32) {
        int j0 = sl * 4;
        float o[4] = {a0 * inv, a1 * inv, a2 * inv, a3 * inv};
#pragma unroll
        for (int j = 0; j < 4; j++) {
            float v = o[j] + ldf(x, n * 128 + j0 + j, f32) + ldf(bias, j0 + j, f32);
            o[j] = v > 0.f ? v : __expf(v) - 1.f;
        }
        *(float4*)(out + (size_t)n * 128 + j0) = make_float4(o[0], o[1], o[2], o[3]);
    }
}

extern "C" void kernel_launch(void* const* d_in, const int* in_sizes, int n_in,
                              void* d_out, int out_size, void* d_ws, size_t ws_size,
                              hipStream_t stream)
{
    const void* x     = d_in[0];
    const int*  ei    = (const int*)d_in[1];
    const void* W     = d_in[2];
    const void* a_src = d_in[3];
    const void* a_trg = d_in[4];
    const void* bias  = d_in[5];
    float* out = (float*)d_out;
    int N = in_sizes[0] / 128;
    int E = N * 16;
    if (in_sizes[1] / 2 < E) E = in_sizes[1] / 2;
    int nbE = (E + 255) / 256;
    int NP1 = N + 1;
    int nbS = (NP1 + 255) / 256;
    int nbZ = (NP1 + 255) / 256;

    char* ws = (char*)d_ws;
    size_t o = 0;
    auto alloc = [&](size_t bytes) {
        size_t r = o;
        o = (o + bytes + 255) & ~(size_t)255;
        return r;
    };
    int* flags = (int*)(ws + alloc(256));
    unsigned short* projb = (unsigned short*)(ws + alloc((size_t)N * 128 * 2));
    float* ssrc  = (float*)(ws + alloc((size_t)N * 4 * 4));
    float* strg  = (float*)(ws + alloc((size_t)N * 4 * 4));
    float* Mval  = (float*)(ws + alloc(256));
    int* counts  = (int*)(ws + alloc((size_t)NP1 * 4));
    int* offsets = (int*)(ws + alloc((size_t)NP1 * 4));
    uint4* epackI = (uint4*)(ws + alloc((size_t)E * 16));
    float4* epackV = (float4*)(ws + alloc((size_t)E * 16));
    uint4* erec  = (uint4*)(ws + alloc((size_t)E * 16));
    float* blockmax = (float*)(ws + alloc((size_t)nbE * 4));
    int* partials = (int*)(ws + alloc((size_t)nbS * 4));
    unsigned short* WhT = (unsigned short*)(ws + alloc(128 * 128 * 2));
    unsigned short* WlT = (unsigned short*)(ws + alloc(128 * 128 * 2));

    k_pre<<<65 + nbZ, 256, 0, stream>>>(x, ei, W, flags, WhT, WlT, counts, N);
    k1_gemm<<<(N + 63) / 64, 256, 0, stream>>>(x, WhT, WlT, a_src, a_trg, flags,
                                               projb, ssrc, strg, N);
    kE_count_max<<<nbE, 256, 0, stream>>>(ei, ssrc, strg, flags, counts, epackI,
                                          epackV, blockmax, E, N);
    kS1_psum<<<nbS, 256, 0, stream>>>(counts, partials, NP1);
    kS2_scanp<<<1, 256, 0, stream>>>(partials, nbS, blockmax, Mval, nbE);
    kS3_offs<<<nbS, 256, 0, stream>>>(counts, partials, offsets, NP1);
    k2c_scatter<<<nbE, 256, 0, stream>>>(epackI, epackV, offsets, Mval, erec, E);
    k3_agg<<<(N + 3) / 4, 256, 0, stream>>>(offsets, erec, projb, x, bias,
                                            flags, out, N, E);
}